// Round 1
// baseline (135.802 us; speedup 1.0000x reference)
//
#include <hip/hip_runtime.h>
#include <math.h>

namespace {
constexpr int Bn = 2, CF = 64;
constexpr int H = 256, W = 256, HW = H * W;
constexpr int IH = 512, IW = 512;

// ws layout in floats
constexpr int OFF_MT   = 0;                        // Mt[y][x], 256*256
constexpr int OFF_GXX  = OFF_MT + 256 * 256;       // [3][256] j-major
constexpr int OFF_GYY  = OFF_GXX + 3 * 256;        // [3][256]
constexpr int OFF_G    = OFF_GYY + 3 * 256;        // 3x3 = w_img^T w_img (pad 16)
constexpr int OFF_RIMG = OFF_G + 16;               // [b][c3][HW]
constexpr int OFF_S    = OFF_RIMG + Bn * 3 * HW;   // sigs: Bn*HW (sigmoid(smap))
constexpr int OFF_PHI  = OFF_S + Bn * HW;          // phi: [b][9][HW]
// PX/PY (32*256 each) overlay the RIMG region: consumed by gram_kernel
// before rimg_kernel writes it (same stream => ordered).
constexpr int OFF_PX   = OFF_RIMG;
constexpr int OFF_PY   = OFF_RIMG + 32 * 256;
}

// ---------------------------------------------------------------------------
// P1: PX[o][t], PY[o][t] sinusoid projections (32x256 transcendentals total).
// ---------------------------------------------------------------------------
__global__ __launch_bounds__(256) void pxy_kernel(
    const float* __restrict__ w_pos,
    float* __restrict__ PX, float* __restrict__ PY)
{
  const int t = threadIdx.x;
  const int o = blockIdx.x;
  float s[16], c[16];
#pragma unroll
  for (int i = 0; i < 16; i++) {
    float d = expf((float)(2 * i) * (-0.2878231366242557f)); // -ln(1e4)/32
    float a = (float)t * d;
    s[i] = sinf(a);
    c[i] = cosf(a);
  }
  const float* wr = w_pos + o * 64;
  float ax = 0.f, ay = 0.f;
#pragma unroll
  for (int i = 0; i < 16; i++) {
    ax += wr[2 * i] * s[i] + wr[2 * i + 1] * c[i];
    ay += wr[32 + 2 * i] * s[i] + wr[33 + 2 * i] * c[i];
  }
  PX[o * 256 + t] = ax;
  PY[o * 256 + t] = ay;
}

// ---------------------------------------------------------------------------
// P2: Mt[t][a] = dot_o(PX[:,a], PY[:,t]); block 0 adds GXX/GYY/G.
// ---------------------------------------------------------------------------
__global__ __launch_bounds__(256) void gram_kernel(
    const float* __restrict__ PX, const float* __restrict__ PY,
    const float* __restrict__ w_img,
    float* __restrict__ Mt, float* __restrict__ GXX, float* __restrict__ GYY,
    float* __restrict__ G)
{
  const int a = threadIdx.x;
  const int t = blockIdx.x;

  float m = 0.f;
#pragma unroll
  for (int o = 0; o < 32; o++) m += PX[o * 256 + a] * PY[o * 256 + t];
  Mt[t * 256 + a] = m;

  if (t == 0) {
#pragma unroll
    for (int j = 0; j < 3; j++) {
      const int nb = a + 2 * (j - 1);
      float gx = 0.f, gy = 0.f;
      if (nb >= 0 && nb < 256) {
#pragma unroll
        for (int o = 0; o < 32; o++) {
          gx += PX[o * 256 + a] * PX[o * 256 + nb];
          gy += PY[o * 256 + a] * PY[o * 256 + nb];
        }
      }
      GXX[j * 256 + a] = gx;
      GYY[j * 256 + a] = gy;
    }
    if (a < 9) {
      const int i = a / 3, j = a % 3;
      float g = 0.f;
#pragma unroll
      for (int o = 0; o < 32; o++) g += w_img[o * 3 + i] * w_img[o * 3 + j];
      G[a] = g;
    }
  }
}

// ---------------------------------------------------------------------------
// rimg: antialiased 2x bilinear downsample of img -> [b][c][HW].
// ---------------------------------------------------------------------------
__device__ __forceinline__ void resize_taps(int p, int n, float w[4], int idx[4])
{
#pragma unroll
  for (int r = 0; r < 4; r++) {
    int q = 2 * p - 1 + r;
    idx[r] = min(max(q, 0), 2 * n - 1);
  }
  if (p == 0)          { w[0] = 0.f;        w[1] = 3.f / 7.f; w[2] = 3.f / 7.f; w[3] = 1.f / 7.f; }
  else if (p == n - 1) { w[0] = 1.f / 7.f;  w[1] = 3.f / 7.f; w[2] = 3.f / 7.f; w[3] = 0.f; }
  else                 { w[0] = 0.125f;     w[1] = 0.375f;    w[2] = 0.375f;    w[3] = 0.125f; }
}

__global__ __launch_bounds__(256) void rimg_kernel(
    const float* __restrict__ img, float* __restrict__ rimg)
{
  const int p = blockIdx.x * 256 + threadIdx.x;
  const int c = blockIdx.y;
  const int b = blockIdx.z;
  const int x = p & (W - 1);
  const int y = p >> 8;

  float wy[4], wx[4];
  int ry[4], rx[4];
  resize_taps(y, H, wy, ry);
  resize_taps(x, W, wx, rx);

  const float* ip = img + ((size_t)(b * 3 + c) * IH) * IW;
  float acc = 0.f;
#pragma unroll
  for (int r = 0; r < 4; r++) {
    const float* rowp = ip + ry[r] * IW;
    float rs = wx[0] * rowp[rx[0]] + wx[1] * rowp[rx[1]] +
               wx[2] * rowp[rx[2]] + wx[3] * rowp[rx[3]];
    acc += wy[r] * rs;
  }
  rimg[((size_t)(b * 3 + c)) * HW + p] = acc;
}

// ---------------------------------------------------------------------------
// sigs[b][p] = sigmoid(dot_c(inp[b,:,p], w_comp)). float4-vectorized:
// thread = (lane -> 4 pixels) x (cg -> 16 channels); LDS float4 reduce.
// Sigmoid applied ONCE here (was 36x per pixel in the old fused kernel).
// ---------------------------------------------------------------------------
__global__ __launch_bounds__(256) void sigs_kernel(
    const float* __restrict__ inp, const float* __restrict__ w_comp,
    float* __restrict__ sigs)
{
  __shared__ float4 red[256];
  const int lane = threadIdx.x & 63;
  const int cg = threadIdx.x >> 6;         // 0..3
  const int p0 = blockIdx.x * 256 + lane * 4;
  const int b = blockIdx.z;

  const float* ib = inp + (size_t)b * CF * HW + (size_t)cg * 16 * HW + p0;
  float4 acc = {0.f, 0.f, 0.f, 0.f};
#pragma unroll
  for (int c = 0; c < 16; c++) {
    const float4 v = *reinterpret_cast<const float4*>(ib + (size_t)c * HW);
    const float wc = w_comp[cg * 16 + c];
    acc.x += v.x * wc; acc.y += v.y * wc;
    acc.z += v.z * wc; acc.w += v.w * wc;
  }
  red[threadIdx.x] = acc;
  __syncthreads();
  if (threadIdx.x < 64) {
    const float4 a = red[threadIdx.x];
    const float4 b1 = red[threadIdx.x + 64];
    const float4 c1 = red[threadIdx.x + 128];
    const float4 d = red[threadIdx.x + 192];
    float4 s;
    s.x = (a.x + b1.x) + (c1.x + d.x);
    s.y = (a.y + b1.y) + (c1.y + d.y);
    s.z = (a.z + b1.z) + (c1.z + d.z);
    s.w = (a.w + b1.w) + (c1.w + d.w);
    s.x = 1.f / (1.f + expf(-s.x));
    s.y = 1.f / (1.f + expf(-s.y));
    s.z = 1.f / (1.f + expf(-s.z));
    s.w = 1.f / (1.f + expf(-s.w));
    *reinterpret_cast<float4*>(sigs + (size_t)b * HW +
                               blockIdx.x * 256 + threadIdx.x * 4) = s;
  }
}

// ---------------------------------------------------------------------------
// phi[b][k][p]: computed ONCE per pixel (was 4x, once per channel group).
// phi[k] = valid_k * sigs[nb_k] * ( rimg(p)^T G rimg(nb_k)
//          + GXX[kx][x] + GYY[ky][y] + Mt[y][cx] + Mt[cy][x] )
// Stored k-major so the gather reads coalesced float4s per k-plane.
// ---------------------------------------------------------------------------
__global__ __launch_bounds__(256) void phi_kernel(
    const float* __restrict__ rimg, const float* __restrict__ sigs,
    const float* __restrict__ Mt, const float* __restrict__ GXX,
    const float* __restrict__ GYY, const float* __restrict__ G,
    float* __restrict__ phi)
{
  const int p = blockIdx.x * 256 + threadIdx.x;
  const int b = blockIdx.y;
  const int x = p & (W - 1);
  const int y = p >> 8;

  const float* rb = rimg + (size_t)b * 3 * HW;
  const float r0 = rb[p], r1 = rb[HW + p], r2 = rb[2 * HW + p];
  const float g0 = G[0], g1 = G[1], g2 = G[2];
  const float g3 = G[3], g4 = G[4], g5 = G[5];
  const float g6 = G[6], g7 = G[7], g8 = G[8];
  const float* sb = sigs + (size_t)b * HW;
  float* phb = phi + (size_t)b * 9 * HW;

#pragma unroll
  for (int k = 0; k < 9; k++) {
    const int ky = k / 3, kx = k % 3;
    const int ny = y + 2 * (ky - 1), nx = x + 2 * (kx - 1);
    const bool valid = ((unsigned)ny < (unsigned)H) & ((unsigned)nx < (unsigned)W);
    const int cy = min(max(ny, 0), H - 1);
    const int cx = min(max(nx, 0), W - 1);
    const int np = cy * W + cx;

    const float n0 = rb[np], n1 = rb[HW + np], n2 = rb[2 * HW + np];
    float fs = r0 * (g0 * n0 + g1 * n1 + g2 * n2)
             + r1 * (g3 * n0 + g4 * n1 + g5 * n2)
             + r2 * (g6 * n0 + g7 * n1 + g8 * n2);
    fs += GXX[kx * 256 + x] + GYY[ky * 256 + y]
        + Mt[y * 256 + cx] + Mt[cy * 256 + x];

    phb[(size_t)k * HW + p] = valid ? sb[np] * fs : 0.f;
  }
}

// ---------------------------------------------------------------------------
// gather: out[c][p] = sum_k phi[k][p] * inp[c][nb_k(p)].
// Each thread owns 4 consecutive pixels. Per channel/row: 3 aligned float4
// window loads (cols x0-4..x0+7); x-shifts (+-2) come from compile-time
// register indices. Out-of-range taps have phi==0, so clamped window
// addresses may read garbage safely (zero-pad semantics preserved).
// ---------------------------------------------------------------------------
__global__ __launch_bounds__(256) void gather_kernel(
    const float* __restrict__ inp, const float* __restrict__ phi,
    float* __restrict__ out)
{
  const int tid = threadIdx.x;
  const int p0 = (blockIdx.y * 256 + tid) * 4;   // 4 px per thread
  const int b = blockIdx.z;
  const int c0 = blockIdx.x * 8;                 // 8 channels per block
  const int x0 = p0 & (W - 1);
  const int y  = p0 >> 8;

  // phi for this thread's 4 pixels, all 9 taps (reused across 8 channels)
  const float* phb = phi + (size_t)b * 9 * HW + p0;
  float4 ph[9];
#pragma unroll
  for (int k = 0; k < 9; k++)
    ph[k] = *reinterpret_cast<const float4*>(phb + (size_t)k * HW);

  // row-window offsets (all 16B-aligned, in-bounds)
  const int xl = max(x0 - 4, 0);
  const int xr = min(x0 + 4, W - 4);
  int off[3][3];
#pragma unroll
  for (int ky = 0; ky < 3; ky++) {
    const int cy = min(max(y + 2 * (ky - 1), 0), H - 1);
    off[ky][0] = cy * W + xl;
    off[ky][1] = cy * W + x0;
    off[ky][2] = cy * W + xr;
  }

  const float* ib = inp + ((size_t)b * CF + c0) * HW;
  float* ob = out + ((size_t)b * CF + c0) * HW + p0;
#pragma unroll 2
  for (int c = 0; c < 8; c++) {
    const float* ic = ib + (size_t)c * HW;
    float4 acc = {0.f, 0.f, 0.f, 0.f};
#pragma unroll
    for (int ky = 0; ky < 3; ky++) {
      const float4 q0 = *reinterpret_cast<const float4*>(ic + off[ky][0]);
      const float4 q1 = *reinterpret_cast<const float4*>(ic + off[ky][1]);
      const float4 q2 = *reinterpret_cast<const float4*>(ic + off[ky][2]);
      const float a[12] = {q0.x, q0.y, q0.z, q0.w,
                           q1.x, q1.y, q1.z, q1.w,
                           q2.x, q2.y, q2.z, q2.w};
#pragma unroll
      for (int kx = 0; kx < 3; kx++) {
        const float4 w = ph[ky * 3 + kx];
        acc.x += w.x * a[2 + 2 * kx + 0];
        acc.y += w.y * a[2 + 2 * kx + 1];
        acc.z += w.z * a[2 + 2 * kx + 2];
        acc.w += w.w * a[2 + 2 * kx + 3];
      }
    }
    *reinterpret_cast<float4*>(ob + (size_t)c * HW) = acc;
  }
}

// ---------------------------------------------------------------------------
extern "C" void kernel_launch(void* const* d_in, const int* in_sizes, int n_in,
                              void* d_out, int out_size, void* d_ws, size_t ws_size,
                              hipStream_t stream)
{
  const float* inp    = (const float*)d_in[0];
  const float* img    = (const float*)d_in[1];
  const float* w_pos  = (const float*)d_in[2];
  const float* w_img  = (const float*)d_in[3];
  const float* w_comp = (const float*)d_in[4];
  float* out = (float*)d_out;
  float* ws  = (float*)d_ws;

  float* Mt   = ws + OFF_MT;
  float* GXX  = ws + OFF_GXX;
  float* GYY  = ws + OFF_GYY;
  float* G    = ws + OFF_G;
  float* rimg = ws + OFF_RIMG;
  float* sigs = ws + OFF_S;
  float* phi  = ws + OFF_PHI;
  float* PX   = ws + OFF_PX;   // overlays rimg (consumed before rimg written)
  float* PY   = ws + OFF_PY;

  hipLaunchKernelGGL(pxy_kernel, dim3(32), dim3(256), 0, stream, w_pos, PX, PY);
  hipLaunchKernelGGL(gram_kernel, dim3(256), dim3(256), 0, stream,
                     PX, PY, w_img, Mt, GXX, GYY, G);

  hipLaunchKernelGGL(rimg_kernel, dim3(HW / 256, 3, Bn), dim3(256), 0, stream,
                     img, rimg);
  hipLaunchKernelGGL(sigs_kernel, dim3(HW / 256, 1, Bn), dim3(256), 0, stream,
                     inp, w_comp, sigs);

  hipLaunchKernelGGL(phi_kernel, dim3(HW / 256, Bn), dim3(256), 0, stream,
                     rimg, sigs, Mt, GXX, GYY, G, phi);

  hipLaunchKernelGGL(gather_kernel, dim3(CF / 8, HW / 1024, Bn), dim3(256), 0, stream,
                     inp, phi, out);
}

// Round 2
// 134.555 us; speedup vs baseline: 1.0093x; 1.0093x over previous
//
#include <hip/hip_runtime.h>
#include <math.h>

namespace {
constexpr int Bn = 2, CF = 64;
constexpr int H = 256, W = 256, HW = H * W;
constexpr int IH = 512, IW = 512;

// ws layout in floats
constexpr int OFF_MT   = 0;                        // Mt[y][x], 256*256
constexpr int OFF_GXX  = OFF_MT + 256 * 256;       // [3][256] j-major
constexpr int OFF_GYY  = OFF_GXX + 3 * 256;        // [3][256]
constexpr int OFF_G    = OFF_GYY + 3 * 256;        // 3x3 = w_img^T w_img (pad 16)
constexpr int OFF_RIMG = OFF_G + 16;               // [b][c3][HW]
constexpr int OFF_S    = OFF_RIMG + Bn * 3 * HW;   // sigs: Bn*HW = sigmoid(smap)
// PX/PY (32*256 each) overlay the RIMG region: consumed by gram_kernel
// before rimg_kernel writes it (same stream => ordered).
constexpr int OFF_PX   = OFF_RIMG;
constexpr int OFF_PY   = OFF_RIMG + 32 * 256;
}

// ---------------------------------------------------------------------------
// P1: PX[o][t], PY[o][t] sinusoid projections (32x256 transcendentals total).
// ---------------------------------------------------------------------------
__global__ __launch_bounds__(256) void pxy_kernel(
    const float* __restrict__ w_pos,
    float* __restrict__ PX, float* __restrict__ PY)
{
  const int t = threadIdx.x;
  const int o = blockIdx.x;
  float s[16], c[16];
#pragma unroll
  for (int i = 0; i < 16; i++) {
    float d = expf((float)(2 * i) * (-0.2878231366242557f)); // -ln(1e4)/32
    float a = (float)t * d;
    s[i] = sinf(a);
    c[i] = cosf(a);
  }
  const float* wr = w_pos + o * 64;
  float ax = 0.f, ay = 0.f;
#pragma unroll
  for (int i = 0; i < 16; i++) {
    ax += wr[2 * i] * s[i] + wr[2 * i + 1] * c[i];
    ay += wr[32 + 2 * i] * s[i] + wr[33 + 2 * i] * c[i];
  }
  PX[o * 256 + t] = ax;
  PY[o * 256 + t] = ay;
}

// ---------------------------------------------------------------------------
// P2: Mt[t][a] = dot_o(PX[:,a], PY[:,t]); block 0 adds GXX/GYY/G.
// ---------------------------------------------------------------------------
__global__ __launch_bounds__(256) void gram_kernel(
    const float* __restrict__ PX, const float* __restrict__ PY,
    const float* __restrict__ w_img,
    float* __restrict__ Mt, float* __restrict__ GXX, float* __restrict__ GYY,
    float* __restrict__ G)
{
  const int a = threadIdx.x;
  const int t = blockIdx.x;

  float m = 0.f;
#pragma unroll
  for (int o = 0; o < 32; o++) m += PX[o * 256 + a] * PY[o * 256 + t];
  Mt[t * 256 + a] = m;

  if (t == 0) {
#pragma unroll
    for (int j = 0; j < 3; j++) {
      const int nb = a + 2 * (j - 1);
      float gx = 0.f, gy = 0.f;
      if (nb >= 0 && nb < 256) {
#pragma unroll
        for (int o = 0; o < 32; o++) {
          gx += PX[o * 256 + a] * PX[o * 256 + nb];
          gy += PY[o * 256 + a] * PY[o * 256 + nb];
        }
      }
      GXX[j * 256 + a] = gx;
      GYY[j * 256 + a] = gy;
    }
    if (a < 9) {
      const int i = a / 3, j = a % 3;
      float g = 0.f;
#pragma unroll
      for (int o = 0; o < 32; o++) g += w_img[o * 3 + i] * w_img[o * 3 + j];
      G[a] = g;
    }
  }
}

// ---------------------------------------------------------------------------
// rimg: antialiased 2x bilinear downsample of img -> [b][c][HW].
// ---------------------------------------------------------------------------
__device__ __forceinline__ void resize_taps(int p, int n, float w[4], int idx[4])
{
#pragma unroll
  for (int r = 0; r < 4; r++) {
    int q = 2 * p - 1 + r;
    idx[r] = min(max(q, 0), 2 * n - 1);
  }
  if (p == 0)          { w[0] = 0.f;        w[1] = 3.f / 7.f; w[2] = 3.f / 7.f; w[3] = 1.f / 7.f; }
  else if (p == n - 1) { w[0] = 1.f / 7.f;  w[1] = 3.f / 7.f; w[2] = 3.f / 7.f; w[3] = 0.f; }
  else                 { w[0] = 0.125f;     w[1] = 0.375f;    w[2] = 0.375f;    w[3] = 0.125f; }
}

__global__ __launch_bounds__(256) void rimg_kernel(
    const float* __restrict__ img, float* __restrict__ rimg)
{
  const int p = blockIdx.x * 256 + threadIdx.x;
  const int c = blockIdx.y;
  const int b = blockIdx.z;
  const int x = p & (W - 1);
  const int y = p >> 8;

  float wy[4], wx[4];
  int ry[4], rx[4];
  resize_taps(y, H, wy, ry);
  resize_taps(x, W, wx, rx);

  const float* ip = img + ((size_t)(b * 3 + c) * IH) * IW;
  float acc = 0.f;
#pragma unroll
  for (int r = 0; r < 4; r++) {
    const float* rowp = ip + ry[r] * IW;
    float rs = wx[0] * rowp[rx[0]] + wx[1] * rowp[rx[1]] +
               wx[2] * rowp[rx[2]] + wx[3] * rowp[rx[3]];
    acc += wy[r] * rs;
  }
  rimg[((size_t)(b * 3 + c)) * HW + p] = acc;
}

// ---------------------------------------------------------------------------
// sigs[b][p] = sigmoid(dot_c(inp[b,:,p], w_comp)). float4-vectorized:
// thread = (lane -> 4 pixels) x (cg -> 16 channels); LDS float4 reduce.
// Sigmoid applied ONCE here (was 36x per pixel in the R0 fused kernel).
// ---------------------------------------------------------------------------
__global__ __launch_bounds__(256) void sigs_kernel(
    const float* __restrict__ inp, const float* __restrict__ w_comp,
    float* __restrict__ sigs)
{
  __shared__ float4 red[256];
  const int lane = threadIdx.x & 63;
  const int cg = threadIdx.x >> 6;         // 0..3
  const int p0 = blockIdx.x * 256 + lane * 4;
  const int b = blockIdx.z;

  const float* ib = inp + (size_t)b * CF * HW + (size_t)cg * 16 * HW + p0;
  float4 acc = {0.f, 0.f, 0.f, 0.f};
#pragma unroll
  for (int c = 0; c < 16; c++) {
    const float4 v = *reinterpret_cast<const float4*>(ib + (size_t)c * HW);
    const float wc = w_comp[cg * 16 + c];
    acc.x += v.x * wc; acc.y += v.y * wc;
    acc.z += v.z * wc; acc.w += v.w * wc;
  }
  red[threadIdx.x] = acc;
  __syncthreads();
  if (threadIdx.x < 64) {
    const float4 a = red[threadIdx.x];
    const float4 b1 = red[threadIdx.x + 64];
    const float4 c1 = red[threadIdx.x + 128];
    const float4 d = red[threadIdx.x + 192];
    float4 s;
    s.x = (a.x + b1.x) + (c1.x + d.x);
    s.y = (a.y + b1.y) + (c1.y + d.y);
    s.z = (a.z + b1.z) + (c1.z + d.z);
    s.w = (a.w + b1.w) + (c1.w + d.w);
    s.x = 1.f / (1.f + expf(-s.x));
    s.y = 1.f / (1.f + expf(-s.y));
    s.z = 1.f / (1.f + expf(-s.z));
    s.w = 1.f / (1.f + expf(-s.w));
    *reinterpret_cast<float4*>(sigs + (size_t)b * HW +
                               blockIdx.x * 256 + threadIdx.x * 4) = s;
  }
}

// ---------------------------------------------------------------------------
// phigather (fused, 4 px/thread): thread owns pixels p0..p0+3 (same row y).
// All x-dependent neighbor reads use an 8-wide window [x0-2 .. x0+5]:
//   L = float2 @ max(x0-2,0), C = float4 @ x0, R = float2 @ min(x0+4, W-2)
//   value(kx, px j) = a[j + 2*kx], a = {L.x,L.y,C.x,C.y,C.z,C.w,R.x,R.y}
// Out-of-range taps have phi==0 (zero-pad semantics), so clamped window
// entries may hold garbage safely.
// Phase 1 (per cg, 4x recompute but vectorized & expf-free):
//   t = G^T r per pixel (9 FMA), then fs(tap) = t . n (3 FMA) + GXX+GYY+Mt+Mt
//   ph[k] = valid * sigs[nb] * fs
// Phase 2: out[c][p] = sum_k ph[k] * inp[c][nb_k], 16 channels, float4 I/O.
// ---------------------------------------------------------------------------
__global__ __launch_bounds__(256) void phigather_kernel(
    const float* __restrict__ inp, const float* __restrict__ rimg,
    const float* __restrict__ sigs, const float* __restrict__ Mt,
    const float* __restrict__ GXX, const float* __restrict__ GYY,
    const float* __restrict__ G, float* __restrict__ out)
{
  const int cg = blockIdx.x;                             // 0..3
  const int p0 = (blockIdx.y * 256 + threadIdx.x) * 4;   // 4 px per thread
  const int b = blockIdx.z;
  const int x0 = p0 & (W - 1);
  const int y  = p0 >> 8;

  const int xl = max(x0 - 2, 0);          // 8B-aligned
  const int xr = min(x0 + 4, W - 2);      // 8B-aligned

  int rowoff[3];
  bool vrow[3];
#pragma unroll
  for (int ky = 0; ky < 3; ky++) {
    const int cy = y + 2 * (ky - 1);
    vrow[ky] = ((unsigned)cy < (unsigned)H);
    rowoff[ky] = min(max(cy, 0), H - 1) * W;
  }

  const float* rb = rimg + (size_t)b * 3 * HW;
  const float* sb = sigs + (size_t)b * HW;

  // t = G^T r per pixel (float4 lanes = the 4 pixels)
  const float4 r0 = *reinterpret_cast<const float4*>(rb + p0);
  const float4 r1 = *reinterpret_cast<const float4*>(rb + HW + p0);
  const float4 r2 = *reinterpret_cast<const float4*>(rb + 2 * HW + p0);
  float4 t0, t1, t2;
  {
    const float g0 = G[0], g1 = G[1], g2 = G[2];
    const float g3 = G[3], g4 = G[4], g5 = G[5];
    const float g6 = G[6], g7 = G[7], g8 = G[8];
    t0.x = r0.x * g0 + r1.x * g3 + r2.x * g6;
    t0.y = r0.y * g0 + r1.y * g3 + r2.y * g6;
    t0.z = r0.z * g0 + r1.z * g3 + r2.z * g6;
    t0.w = r0.w * g0 + r1.w * g3 + r2.w * g6;
    t1.x = r0.x * g1 + r1.x * g4 + r2.x * g7;
    t1.y = r0.y * g1 + r1.y * g4 + r2.y * g7;
    t1.z = r0.z * g1 + r1.z * g4 + r2.z * g7;
    t1.w = r0.w * g1 + r1.w * g4 + r2.w * g7;
    t2.x = r0.x * g2 + r1.x * g5 + r2.x * g8;
    t2.y = r0.y * g2 + r1.y * g5 + r2.y * g8;
    t2.z = r0.z * g2 + r1.z * g5 + r2.z * g8;
    t2.w = r0.w * g2 + r1.w * g5 + r2.w * g8;
  }

  // Mt row-y window (shared by all ky)
  float mrow[8];
  {
    const float2 L = *reinterpret_cast<const float2*>(Mt + y * W + xl);
    const float4 C = *reinterpret_cast<const float4*>(Mt + y * W + x0);
    const float2 R = *reinterpret_cast<const float2*>(Mt + y * W + xr);
    mrow[0] = L.x; mrow[1] = L.y; mrow[2] = C.x; mrow[3] = C.y;
    mrow[4] = C.z; mrow[5] = C.w; mrow[6] = R.x; mrow[7] = R.y;
  }
  // GXX[kx][x0..x0+3] (aligned)
  float4 gxxv[3];
#pragma unroll
  for (int kx = 0; kx < 3; kx++)
    gxxv[kx] = *reinterpret_cast<const float4*>(GXX + kx * 256 + x0);

  float4 ph[9];
#pragma unroll
  for (int ky = 0; ky < 3; ky++) {
    const int ro = rowoff[ky];
    float a0[8], a1[8], a2[8], as_[8];
    {
      const float2 L0 = *reinterpret_cast<const float2*>(rb + ro + xl);
      const float4 C0 = *reinterpret_cast<const float4*>(rb + ro + x0);
      const float2 R0 = *reinterpret_cast<const float2*>(rb + ro + xr);
      a0[0]=L0.x; a0[1]=L0.y; a0[2]=C0.x; a0[3]=C0.y;
      a0[4]=C0.z; a0[5]=C0.w; a0[6]=R0.x; a0[7]=R0.y;
      const float2 L1 = *reinterpret_cast<const float2*>(rb + HW + ro + xl);
      const float4 C1 = *reinterpret_cast<const float4*>(rb + HW + ro + x0);
      const float2 R1 = *reinterpret_cast<const float2*>(rb + HW + ro + xr);
      a1[0]=L1.x; a1[1]=L1.y; a1[2]=C1.x; a1[3]=C1.y;
      a1[4]=C1.z; a1[5]=C1.w; a1[6]=R1.x; a1[7]=R1.y;
      const float2 L2 = *reinterpret_cast<const float2*>(rb + 2 * HW + ro + xl);
      const float4 C2 = *reinterpret_cast<const float4*>(rb + 2 * HW + ro + x0);
      const float2 R2 = *reinterpret_cast<const float2*>(rb + 2 * HW + ro + xr);
      a2[0]=L2.x; a2[1]=L2.y; a2[2]=C2.x; a2[3]=C2.y;
      a2[4]=C2.z; a2[5]=C2.w; a2[6]=R2.x; a2[7]=R2.y;
      const float2 Ls = *reinterpret_cast<const float2*>(sb + ro + xl);
      const float4 Cs = *reinterpret_cast<const float4*>(sb + ro + x0);
      const float2 Rs = *reinterpret_cast<const float2*>(sb + ro + xr);
      as_[0]=Ls.x; as_[1]=Ls.y; as_[2]=Cs.x; as_[3]=Cs.y;
      as_[4]=Cs.z; as_[5]=Cs.w; as_[6]=Rs.x; as_[7]=Rs.y;
    }
    const float4 mc = *reinterpret_cast<const float4*>(Mt + ro + x0);
    const float gyy = GYY[ky * 256 + y];

#pragma unroll
    for (int kx = 0; kx < 3; kx++) {
      float4 p;
      {
        const int rel = 0 + 2 * kx;
        const float fs = t0.x * a0[rel] + t1.x * a1[rel] + t2.x * a2[rel]
                       + gxxv[kx].x + gyy + mrow[rel] + mc.x;
        const bool v = vrow[ky] && ((unsigned)(x0 + 0 + 2 * (kx - 1)) < (unsigned)W);
        p.x = v ? as_[rel] * fs : 0.f;
      }
      {
        const int rel = 1 + 2 * kx;
        const float fs = t0.y * a0[rel] + t1.y * a1[rel] + t2.y * a2[rel]
                       + gxxv[kx].y + gyy + mrow[rel] + mc.y;
        const bool v = vrow[ky] && ((unsigned)(x0 + 1 + 2 * (kx - 1)) < (unsigned)W);
        p.y = v ? as_[rel] * fs : 0.f;
      }
      {
        const int rel = 2 + 2 * kx;
        const float fs = t0.z * a0[rel] + t1.z * a1[rel] + t2.z * a2[rel]
                       + gxxv[kx].z + gyy + mrow[rel] + mc.z;
        const bool v = vrow[ky] && ((unsigned)(x0 + 2 + 2 * (kx - 1)) < (unsigned)W);
        p.z = v ? as_[rel] * fs : 0.f;
      }
      {
        const int rel = 3 + 2 * kx;
        const float fs = t0.w * a0[rel] + t1.w * a1[rel] + t2.w * a2[rel]
                       + gxxv[kx].w + gyy + mrow[rel] + mc.w;
        const bool v = vrow[ky] && ((unsigned)(x0 + 3 + 2 * (kx - 1)) < (unsigned)W);
        p.w = v ? as_[rel] * fs : 0.f;
      }
      ph[ky * 3 + kx] = p;
    }
  }

  // phase 2: 16 channels, float4 in/out
  const float* ib = inp + ((size_t)b * CF + cg * 16) * HW;
  float* ob = out + ((size_t)b * CF + cg * 16) * HW + p0;
#pragma unroll 4
  for (int c = 0; c < 16; c++) {
    const float* ic = ib + (size_t)c * HW;
    float4 acc = {0.f, 0.f, 0.f, 0.f};
#pragma unroll
    for (int ky = 0; ky < 3; ky++) {
      const int ro = rowoff[ky];
      const float2 L = *reinterpret_cast<const float2*>(ic + ro + xl);
      const float4 C = *reinterpret_cast<const float4*>(ic + ro + x0);
      const float2 R = *reinterpret_cast<const float2*>(ic + ro + xr);
      const float a[8] = {L.x, L.y, C.x, C.y, C.z, C.w, R.x, R.y};
#pragma unroll
      for (int kx = 0; kx < 3; kx++) {
        const float4 w = ph[ky * 3 + kx];
        acc.x += w.x * a[0 + 2 * kx];
        acc.y += w.y * a[1 + 2 * kx];
        acc.z += w.z * a[2 + 2 * kx];
        acc.w += w.w * a[3 + 2 * kx];
      }
    }
    *reinterpret_cast<float4*>(ob + (size_t)c * HW) = acc;
  }
}

// ---------------------------------------------------------------------------
extern "C" void kernel_launch(void* const* d_in, const int* in_sizes, int n_in,
                              void* d_out, int out_size, void* d_ws, size_t ws_size,
                              hipStream_t stream)
{
  const float* inp    = (const float*)d_in[0];
  const float* img    = (const float*)d_in[1];
  const float* w_pos  = (const float*)d_in[2];
  const float* w_img  = (const float*)d_in[3];
  const float* w_comp = (const float*)d_in[4];
  float* out = (float*)d_out;
  float* ws  = (float*)d_ws;

  float* Mt   = ws + OFF_MT;
  float* GXX  = ws + OFF_GXX;
  float* GYY  = ws + OFF_GYY;
  float* G    = ws + OFF_G;
  float* rimg = ws + OFF_RIMG;
  float* sigs = ws + OFF_S;
  float* PX   = ws + OFF_PX;   // overlays rimg (consumed before rimg written)
  float* PY   = ws + OFF_PY;

  hipLaunchKernelGGL(pxy_kernel, dim3(32), dim3(256), 0, stream, w_pos, PX, PY);
  hipLaunchKernelGGL(gram_kernel, dim3(256), dim3(256), 0, stream,
                     PX, PY, w_img, Mt, GXX, GYY, G);

  hipLaunchKernelGGL(rimg_kernel, dim3(HW / 256, 3, Bn), dim3(256), 0, stream,
                     img, rimg);
  hipLaunchKernelGGL(sigs_kernel, dim3(HW / 256, 1, Bn), dim3(256), 0, stream,
                     inp, w_comp, sigs);

  hipLaunchKernelGGL(phigather_kernel, dim3(CF / 16, HW / 1024, Bn), dim3(256), 0, stream,
                     inp, rimg, sigs, Mt, GXX, GYY, G, out);
}

// Round 4
// 121.677 us; speedup vs baseline: 1.1161x; 1.1058x over previous
//
#include <hip/hip_runtime.h>
#include <math.h>

namespace {
constexpr int Bn = 2, CF = 64;
constexpr int H = 256, W = 256, HW = H * W;
constexpr int IH = 512, IW = 512;

// ws layout in floats
constexpr int OFF_MT   = 0;                        // Mt[y][x], 256*256
constexpr int OFF_GXX  = OFF_MT + 256 * 256;       // [3][256] j-major
constexpr int OFF_GYY  = OFF_GXX + 3 * 256;        // [3][256]
constexpr int OFF_G    = OFF_GYY + 3 * 256;        // 3x3 = w_img^T w_img (pad 16)
constexpr int OFF_RIMG = OFF_G + 16;               // [b][c3][HW]
constexpr int OFF_S    = OFF_RIMG + Bn * 3 * HW;   // sigs: Bn*HW = sigmoid(smap)
// PX/PY (32*256 each) overlay the RIMG region: consumed by gram_kernel
// before prep_kernel writes rimg (same stream => ordered).
constexpr int OFF_PX   = OFF_RIMG;
constexpr int OFF_PY   = OFF_RIMG + 32 * 256;

constexpr int RIMG_BLOCKS = Bn * 3 * (HW / 256);   // 1536
constexpr int SIGS_BLOCKS = Bn * (HW / 64);        // 2048
}

// ---------------------------------------------------------------------------
// P1: PX[o][t], PY[o][t] sinusoid projections (32x256 transcendentals total).
// ---------------------------------------------------------------------------
__global__ __launch_bounds__(256) void pxy_kernel(
    const float* __restrict__ w_pos,
    float* __restrict__ PX, float* __restrict__ PY)
{
  const int t = threadIdx.x;
  const int o = blockIdx.x;
  float s[16], c[16];
#pragma unroll
  for (int i = 0; i < 16; i++) {
    float d = expf((float)(2 * i) * (-0.2878231366242557f)); // -ln(1e4)/32
    float a = (float)t * d;
    s[i] = sinf(a);
    c[i] = cosf(a);
  }
  const float* wr = w_pos + o * 64;
  float ax = 0.f, ay = 0.f;
#pragma unroll
  for (int i = 0; i < 16; i++) {
    ax += wr[2 * i] * s[i] + wr[2 * i + 1] * c[i];
    ay += wr[32 + 2 * i] * s[i] + wr[33 + 2 * i] * c[i];
  }
  PX[o * 256 + t] = ax;
  PY[o * 256 + t] = ay;
}

// ---------------------------------------------------------------------------
// P2: Mt[t][a] = dot_o(PX[:,a], PY[:,t]); block 0 adds GXX/GYY/G.
// ---------------------------------------------------------------------------
__global__ __launch_bounds__(256) void gram_kernel(
    const float* __restrict__ PX, const float* __restrict__ PY,
    const float* __restrict__ w_img,
    float* __restrict__ Mt, float* __restrict__ GXX, float* __restrict__ GYY,
    float* __restrict__ G)
{
  const int a = threadIdx.x;
  const int t = blockIdx.x;

  float m = 0.f;
#pragma unroll
  for (int o = 0; o < 32; o++) m += PX[o * 256 + a] * PY[o * 256 + t];
  Mt[t * 256 + a] = m;

  if (t == 0) {
#pragma unroll
    for (int j = 0; j < 3; j++) {
      const int nb = a + 2 * (j - 1);
      float gx = 0.f, gy = 0.f;
      if (nb >= 0 && nb < 256) {
#pragma unroll
        for (int o = 0; o < 32; o++) {
          gx += PX[o * 256 + a] * PX[o * 256 + nb];
          gy += PY[o * 256 + a] * PY[o * 256 + nb];
        }
      }
      GXX[j * 256 + a] = gx;
      GYY[j * 256 + a] = gy;
    }
    if (a < 9) {
      const int i = a / 3, j = a % 3;
      float g = 0.f;
#pragma unroll
      for (int o = 0; o < 32; o++) g += w_img[o * 3 + i] * w_img[o * 3 + j];
      G[a] = g;
    }
  }
}

// ---------------------------------------------------------------------------
// prep (fused): blocks [0,1536) do the rimg 2x antialiased downsample;
// blocks [1536,3584) compute sigs[b][p] = sigmoid(dot_c(inp, w_comp)).
// Both parts use the proven high-grid R0 structures (latency-bound phases
// need waves, not fewer instructions). One launch instead of two.
// ---------------------------------------------------------------------------
__device__ __forceinline__ void resize_taps(int p, int n, float w[4], int idx[4])
{
#pragma unroll
  for (int r = 0; r < 4; r++) {
    int q = 2 * p - 1 + r;
    idx[r] = min(max(q, 0), 2 * n - 1);
  }
  if (p == 0)          { w[0] = 0.f;        w[1] = 3.f / 7.f; w[2] = 3.f / 7.f; w[3] = 1.f / 7.f; }
  else if (p == n - 1) { w[0] = 1.f / 7.f;  w[1] = 3.f / 7.f; w[2] = 3.f / 7.f; w[3] = 0.f; }
  else                 { w[0] = 0.125f;     w[1] = 0.375f;    w[2] = 0.375f;    w[3] = 0.125f; }
}

__global__ __launch_bounds__(256) void prep_kernel(
    const float* __restrict__ img, const float* __restrict__ inp,
    const float* __restrict__ w_comp,
    float* __restrict__ rimg, float* __restrict__ sigs)
{
  __shared__ float red[256];
  const int gid = blockIdx.x;

  if (gid < RIMG_BLOCKS) {
    // ---- rimg part ----
    const int b = gid / 768;
    const int rem = gid % 768;
    const int c = rem / 256;
    const int p = (rem % 256) * 256 + threadIdx.x;
    const int x = p & (W - 1);
    const int y = p >> 8;

    float wy[4], wx[4];
    int ry[4], rx[4];
    resize_taps(y, H, wy, ry);
    resize_taps(x, W, wx, rx);

    const float* ip = img + ((size_t)(b * 3 + c) * IH) * IW;
    float acc = 0.f;
#pragma unroll
    for (int r = 0; r < 4; r++) {
      const float* rowp = ip + ry[r] * IW;
      float rs = wx[0] * rowp[rx[0]] + wx[1] * rowp[rx[1]] +
                 wx[2] * rowp[rx[2]] + wx[3] * rowp[rx[3]];
      acc += wy[r] * rs;
    }
    rimg[((size_t)(b * 3 + c)) * HW + p] = acc;
  } else {
    // ---- sigs part: 64 px per block, 4 channel-groups, LDS reduce ----
    const int j = gid - RIMG_BLOCKS;
    const int b = j / (HW / 64);
    const int pblk = j % (HW / 64);
    const int lane = threadIdx.x & 63;
    const int cg = threadIdx.x >> 6;         // 0..3
    const int p = pblk * 64 + lane;

    const float* ib = inp + (size_t)b * CF * HW + (size_t)cg * 16 * HW + p;
    float a0 = 0.f, a1 = 0.f, a2 = 0.f, a3 = 0.f;
#pragma unroll
    for (int c = 0; c < 16; c += 4) {
      a0 += ib[(size_t)(c + 0) * HW] * w_comp[cg * 16 + c + 0];
      a1 += ib[(size_t)(c + 1) * HW] * w_comp[cg * 16 + c + 1];
      a2 += ib[(size_t)(c + 2) * HW] * w_comp[cg * 16 + c + 2];
      a3 += ib[(size_t)(c + 3) * HW] * w_comp[cg * 16 + c + 3];
    }
    red[threadIdx.x] = (a0 + a1) + (a2 + a3);
    __syncthreads();
    if (threadIdx.x < 64) {
      const float s = red[threadIdx.x] + red[threadIdx.x + 64] +
                      red[threadIdx.x + 128] + red[threadIdx.x + 192];
      sigs[(size_t)b * HW + pblk * 64 + threadIdx.x] = 1.f / (1.f + expf(-s));
    }
  }
}

// ---------------------------------------------------------------------------
// phigather (fused, 4 px/thread, 8 channels/block -> 1024 blocks = 4 waves
// per SIMD; R2's 512 blocks = 2/SIMD was the occupancy regression).
// Window trick: all x-dependent neighbor reads use an 8-wide window
// [x0-2 .. x0+5]: L=float2@max(x0-2,0), C=float4@x0, R=float2@min(x0+4,W-2);
// value(kx, px j) = a[j+2*kx]. Out-of-range taps have phi==0 (zero-pad),
// so clamped window entries may hold garbage safely.
// Phase 1: t = G^T r (9 FMA/px), fs(tap) = t.n + GXX+GYY+Mt_row+Mt_col;
// ph[k] = valid * sigs[nb] * fs  (expf-free; sigmoid precomputed in prep).
// Phase 2: out[c][p] = sum_k ph[k] * inp[c][nb_k], 8 channels, float4 I/O.
// ---------------------------------------------------------------------------
__global__ __launch_bounds__(256) void phigather_kernel(
    const float* __restrict__ inp, const float* __restrict__ rimg,
    const float* __restrict__ sigs, const float* __restrict__ Mt,
    const float* __restrict__ GXX, const float* __restrict__ GYY,
    const float* __restrict__ G, float* __restrict__ out)
{
  const int cg = blockIdx.x;                             // 0..7, 8 channels
  const int p0 = (blockIdx.y * 256 + threadIdx.x) * 4;   // 4 px per thread
  const int b = blockIdx.z;
  const int x0 = p0 & (W - 1);
  const int y  = p0 >> 8;

  const int xl = max(x0 - 2, 0);          // 8B-aligned
  const int xr = min(x0 + 4, W - 2);      // 8B-aligned

  int rowoff[3];
  bool vrow[3];
#pragma unroll
  for (int ky = 0; ky < 3; ky++) {
    const int cy = y + 2 * (ky - 1);
    vrow[ky] = ((unsigned)cy < (unsigned)H);
    rowoff[ky] = min(max(cy, 0), H - 1) * W;
  }

  const float* rb = rimg + (size_t)b * 3 * HW;
  const float* sb = sigs + (size_t)b * HW;

  // t = G^T r per pixel (float4 lanes = the 4 pixels)
  const float4 r0 = *reinterpret_cast<const float4*>(rb + p0);
  const float4 r1 = *reinterpret_cast<const float4*>(rb + HW + p0);
  const float4 r2 = *reinterpret_cast<const float4*>(rb + 2 * HW + p0);
  float4 t0, t1, t2;
  {
    const float g0 = G[0], g1 = G[1], g2 = G[2];
    const float g3 = G[3], g4 = G[4], g5 = G[5];
    const float g6 = G[6], g7 = G[7], g8 = G[8];
    t0.x = r0.x * g0 + r1.x * g3 + r2.x * g6;
    t0.y = r0.y * g0 + r1.y * g3 + r2.y * g6;
    t0.z = r0.z * g0 + r1.z * g3 + r2.z * g6;
    t0.w = r0.w * g0 + r1.w * g3 + r2.w * g6;
    t1.x = r0.x * g1 + r1.x * g4 + r2.x * g7;
    t1.y = r0.y * g1 + r1.y * g4 + r2.y * g7;
    t1.z = r0.z * g1 + r1.z * g4 + r2.z * g7;
    t1.w = r0.w * g1 + r1.w * g4 + r2.w * g7;
    t2.x = r0.x * g2 + r1.x * g5 + r2.x * g8;
    t2.y = r0.y * g2 + r1.y * g5 + r2.y * g8;
    t2.z = r0.z * g2 + r1.z * g5 + r2.z * g8;
    t2.w = r0.w * g2 + r1.w * g5 + r2.w * g8;
  }

  // Mt row-y window (shared by all ky)
  float mrow[8];
  {
    const float2 L = *reinterpret_cast<const float2*>(Mt + y * W + xl);
    const float4 C = *reinterpret_cast<const float4*>(Mt + y * W + x0);
    const float2 R = *reinterpret_cast<const float2*>(Mt + y * W + xr);
    mrow[0] = L.x; mrow[1] = L.y; mrow[2] = C.x; mrow[3] = C.y;
    mrow[4] = C.z; mrow[5] = C.w; mrow[6] = R.x; mrow[7] = R.y;
  }
  // GXX[kx][x0..x0+3] (aligned)
  float4 gxxv[3];
#pragma unroll
  for (int kx = 0; kx < 3; kx++)
    gxxv[kx] = *reinterpret_cast<const float4*>(GXX + kx * 256 + x0);

  float4 ph[9];
#pragma unroll
  for (int ky = 0; ky < 3; ky++) {
    const int ro = rowoff[ky];
    float a0[8], a1[8], a2[8], as_[8];
    {
      const float2 L0 = *reinterpret_cast<const float2*>(rb + ro + xl);
      const float4 C0 = *reinterpret_cast<const float4*>(rb + ro + x0);
      const float2 R0 = *reinterpret_cast<const float2*>(rb + ro + xr);
      a0[0]=L0.x; a0[1]=L0.y; a0[2]=C0.x; a0[3]=C0.y;
      a0[4]=C0.z; a0[5]=C0.w; a0[6]=R0.x; a0[7]=R0.y;
      const float2 L1 = *reinterpret_cast<const float2*>(rb + HW + ro + xl);
      const float4 C1 = *reinterpret_cast<const float4*>(rb + HW + ro + x0);
      const float2 R1 = *reinterpret_cast<const float2*>(rb + HW + ro + xr);
      a1[0]=L1.x; a1[1]=L1.y; a1[2]=C1.x; a1[3]=C1.y;
      a1[4]=C1.z; a1[5]=C1.w; a1[6]=R1.x; a1[7]=R1.y;
      const float2 L2 = *reinterpret_cast<const float2*>(rb + 2 * HW + ro + xl);
      const float4 C2 = *reinterpret_cast<const float4*>(rb + 2 * HW + ro + x0);
      const float2 R2 = *reinterpret_cast<const float2*>(rb + 2 * HW + ro + xr);
      a2[0]=L2.x; a2[1]=L2.y; a2[2]=C2.x; a2[3]=C2.y;
      a2[4]=C2.z; a2[5]=C2.w; a2[6]=R2.x; a2[7]=R2.y;
      const float2 Ls = *reinterpret_cast<const float2*>(sb + ro + xl);
      const float4 Cs = *reinterpret_cast<const float4*>(sb + ro + x0);
      const float2 Rs = *reinterpret_cast<const float2*>(sb + ro + xr);
      as_[0]=Ls.x; as_[1]=Ls.y; as_[2]=Cs.x; as_[3]=Cs.y;
      as_[4]=Cs.z; as_[5]=Cs.w; as_[6]=Rs.x; as_[7]=Rs.y;
    }
    const float4 mc = *reinterpret_cast<const float4*>(Mt + ro + x0);
    const float gyy = GYY[ky * 256 + y];

#pragma unroll
    for (int kx = 0; kx < 3; kx++) {
      float4 p;
      {
        const int rel = 0 + 2 * kx;
        const float fs = t0.x * a0[rel] + t1.x * a1[rel] + t2.x * a2[rel]
                       + gxxv[kx].x + gyy + mrow[rel] + mc.x;
        const bool v = vrow[ky] && ((unsigned)(x0 + 0 + 2 * (kx - 1)) < (unsigned)W);
        p.x = v ? as_[rel] * fs : 0.f;
      }
      {
        const int rel = 1 + 2 * kx;
        const float fs = t0.y * a0[rel] + t1.y * a1[rel] + t2.y * a2[rel]
                       + gxxv[kx].y + gyy + mrow[rel] + mc.y;
        const bool v = vrow[ky] && ((unsigned)(x0 + 1 + 2 * (kx - 1)) < (unsigned)W);
        p.y = v ? as_[rel] * fs : 0.f;
      }
      {
        const int rel = 2 + 2 * kx;
        const float fs = t0.z * a0[rel] + t1.z * a1[rel] + t2.z * a2[rel]
                       + gxxv[kx].z + gyy + mrow[rel] + mc.z;
        const bool v = vrow[ky] && ((unsigned)(x0 + 2 + 2 * (kx - 1)) < (unsigned)W);
        p.z = v ? as_[rel] * fs : 0.f;
      }
      {
        const int rel = 3 + 2 * kx;
        const float fs = t0.w * a0[rel] + t1.w * a1[rel] + t2.w * a2[rel]
                       + gxxv[kx].w + gyy + mrow[rel] + mc.w;
        const bool v = vrow[ky] && ((unsigned)(x0 + 3 + 2 * (kx - 1)) < (unsigned)W);
        p.w = v ? as_[rel] * fs : 0.f;
      }
      ph[ky * 3 + kx] = p;
    }
  }

  // phase 2: 8 channels, float4 in/out
  const float* ib = inp + ((size_t)b * CF + cg * 8) * HW;
  float* ob = out + ((size_t)b * CF + cg * 8) * HW + p0;
#pragma unroll 4
  for (int c = 0; c < 8; c++) {
    const float* ic = ib + (size_t)c * HW;
    float4 acc = {0.f, 0.f, 0.f, 0.f};
#pragma unroll
    for (int ky = 0; ky < 3; ky++) {
      const int ro = rowoff[ky];
      const float2 L = *reinterpret_cast<const float2*>(ic + ro + xl);
      const float4 C = *reinterpret_cast<const float4*>(ic + ro + x0);
      const float2 R = *reinterpret_cast<const float2*>(ic + ro + xr);
      const float a[8] = {L.x, L.y, C.x, C.y, C.z, C.w, R.x, R.y};
#pragma unroll
      for (int kx = 0; kx < 3; kx++) {
        const float4 w = ph[ky * 3 + kx];
        acc.x += w.x * a[0 + 2 * kx];
        acc.y += w.y * a[1 + 2 * kx];
        acc.z += w.z * a[2 + 2 * kx];
        acc.w += w.w * a[3 + 2 * kx];
      }
    }
    *reinterpret_cast<float4*>(ob + (size_t)c * HW) = acc;
  }
}

// ---------------------------------------------------------------------------
extern "C" void kernel_launch(void* const* d_in, const int* in_sizes, int n_in,
                              void* d_out, int out_size, void* d_ws, size_t ws_size,
                              hipStream_t stream)
{
  const float* inp    = (const float*)d_in[0];
  const float* img    = (const float*)d_in[1];
  const float* w_pos  = (const float*)d_in[2];
  const float* w_img  = (const float*)d_in[3];
  const float* w_comp = (const float*)d_in[4];
  float* out = (float*)d_out;
  float* ws  = (float*)d_ws;

  float* Mt   = ws + OFF_MT;
  float* GXX  = ws + OFF_GXX;
  float* GYY  = ws + OFF_GYY;
  float* G    = ws + OFF_G;
  float* rimg = ws + OFF_RIMG;
  float* sigs = ws + OFF_S;
  float* PX   = ws + OFF_PX;   // overlays rimg (consumed before rimg written)
  float* PY   = ws + OFF_PY;

  hipLaunchKernelGGL(pxy_kernel, dim3(32), dim3(256), 0, stream, w_pos, PX, PY);
  hipLaunchKernelGGL(gram_kernel, dim3(256), dim3(256), 0, stream,
                     PX, PY, w_img, Mt, GXX, GYY, G);

  hipLaunchKernelGGL(prep_kernel, dim3(RIMG_BLOCKS + SIGS_BLOCKS), dim3(256), 0, stream,
                     img, inp, w_comp, rimg, sigs);

  hipLaunchKernelGGL(phigather_kernel, dim3(8, HW / 1024, Bn), dim3(256), 0, stream,
                     inp, rimg, sigs, Mt, GXX, GYY, G, out);
}

// Round 5
// 118.608 us; speedup vs baseline: 1.1450x; 1.0259x over previous
//
#include <hip/hip_runtime.h>
#include <math.h>

namespace {
constexpr int Bn = 2, CF = 64;
constexpr int H = 256, W = 256, HW = H * W;
constexpr int IH = 512, IW = 512;

// ws layout in floats (no overlays — ws is far larger than we need)
constexpr int OFF_MT   = 0;                        // Mt[y][x], 256*256
constexpr int OFF_GXX  = OFF_MT + 256 * 256;       // [3][256] j-major
constexpr int OFF_GYY  = OFF_GXX + 3 * 256;        // [3][256]
constexpr int OFF_G    = OFF_GYY + 3 * 256;        // 3x3 = w_img^T w_img (pad 16)
constexpr int OFF_RIMG = OFF_G + 16;               // [b][c3][HW]
constexpr int OFF_S    = OFF_RIMG + Bn * 3 * HW;   // sigs: Bn*HW = sigmoid(smap)
constexpr int OFF_PX   = OFF_S + Bn * HW;          // [32][256]
constexpr int OFF_PY   = OFF_PX + 32 * 256;        // [32][256]

// fused prep partition
constexpr int GRAM_BLOCKS = 256;
constexpr int RIMG_BLOCKS = Bn * 3 * (HW / 256);   // 1536
constexpr int SIGS_BLOCKS = Bn * (HW / 256);       // 512 (float4, 4 px/thread)
constexpr int PREP_BLOCKS = GRAM_BLOCKS + RIMG_BLOCKS + SIGS_BLOCKS; // 2304
}

// ---------------------------------------------------------------------------
// P1: PX[o][t], PY[o][t] sinusoid projections (32x256 transcendentals total;
// NOT per-Mt-row — that was the old 43us mistake).
// ---------------------------------------------------------------------------
__global__ __launch_bounds__(256) void pxy_kernel(
    const float* __restrict__ w_pos,
    float* __restrict__ PX, float* __restrict__ PY)
{
  const int t = threadIdx.x;
  const int o = blockIdx.x;
  float s[16], c[16];
#pragma unroll
  for (int i = 0; i < 16; i++) {
    float d = expf((float)(2 * i) * (-0.2878231366242557f)); // -ln(1e4)/32
    float a = (float)t * d;
    s[i] = sinf(a);
    c[i] = cosf(a);
  }
  const float* wr = w_pos + o * 64;
  float ax = 0.f, ay = 0.f;
#pragma unroll
  for (int i = 0; i < 16; i++) {
    ax += wr[2 * i] * s[i] + wr[2 * i + 1] * c[i];
    ay += wr[32 + 2 * i] * s[i] + wr[33 + 2 * i] * c[i];
  }
  PX[o * 256 + t] = ax;
  PY[o * 256 + t] = ay;
}

// ---------------------------------------------------------------------------
// prep (fused, 2304 blocks):
//   [0,256)        gram: Mt[t][a] = dot_o(PX[:,a],PY[:,t]); blk 0 adds
//                  GXX/GYY/G. Small, L2-resident — overlaps rimg/sigs traffic
//                  instead of costing its own serialized dispatch.
//   [256,1792)     rimg: antialiased 2x bilinear downsample of img.
//   [1792,2304)    sigs: sigmoid(dot_c(inp,w_comp)) with float4 loads
//                  (4 px/thread, 4x fewer VMEM instructions than scalar).
// All branches are block-uniform; __syncthreads only in the sigs branch.
// ---------------------------------------------------------------------------
__device__ __forceinline__ void resize_taps(int p, int n, float w[4], int idx[4])
{
#pragma unroll
  for (int r = 0; r < 4; r++) {
    int q = 2 * p - 1 + r;
    idx[r] = min(max(q, 0), 2 * n - 1);
  }
  if (p == 0)          { w[0] = 0.f;        w[1] = 3.f / 7.f; w[2] = 3.f / 7.f; w[3] = 1.f / 7.f; }
  else if (p == n - 1) { w[0] = 1.f / 7.f;  w[1] = 3.f / 7.f; w[2] = 3.f / 7.f; w[3] = 0.f; }
  else                 { w[0] = 0.125f;     w[1] = 0.375f;    w[2] = 0.375f;    w[3] = 0.125f; }
}

__global__ __launch_bounds__(256) void prep_kernel(
    const float* __restrict__ img, const float* __restrict__ inp,
    const float* __restrict__ w_comp, const float* __restrict__ w_img,
    const float* __restrict__ PX, const float* __restrict__ PY,
    float* __restrict__ rimg, float* __restrict__ sigs,
    float* __restrict__ Mt, float* __restrict__ GXX, float* __restrict__ GYY,
    float* __restrict__ G)
{
  __shared__ float4 red4[256];
  const int gid = blockIdx.x;

  if (gid < GRAM_BLOCKS) {
    // ---- gram part ----
    const int a = threadIdx.x;
    const int t = gid;

    float m = 0.f;
#pragma unroll
    for (int o = 0; o < 32; o++) m += PX[o * 256 + a] * PY[o * 256 + t];
    Mt[t * 256 + a] = m;

    if (t == 0) {
#pragma unroll
      for (int j = 0; j < 3; j++) {
        const int nb = a + 2 * (j - 1);
        float gx = 0.f, gy = 0.f;
        if (nb >= 0 && nb < 256) {
#pragma unroll
          for (int o = 0; o < 32; o++) {
            gx += PX[o * 256 + a] * PX[o * 256 + nb];
            gy += PY[o * 256 + a] * PY[o * 256 + nb];
          }
        }
        GXX[j * 256 + a] = gx;
        GYY[j * 256 + a] = gy;
      }
      if (a < 9) {
        const int i = a / 3, j = a % 3;
        float g = 0.f;
#pragma unroll
        for (int o = 0; o < 32; o++) g += w_img[o * 3 + i] * w_img[o * 3 + j];
        G[a] = g;
      }
    }
  } else if (gid < GRAM_BLOCKS + RIMG_BLOCKS) {
    // ---- rimg part ----
    const int rid = gid - GRAM_BLOCKS;
    const int b = rid / 768;
    const int rem = rid % 768;
    const int c = rem / 256;
    const int p = (rem % 256) * 256 + threadIdx.x;
    const int x = p & (W - 1);
    const int y = p >> 8;

    float wy[4], wx[4];
    int ry[4], rx[4];
    resize_taps(y, H, wy, ry);
    resize_taps(x, W, wx, rx);

    const float* ip = img + ((size_t)(b * 3 + c) * IH) * IW;
    float acc = 0.f;
#pragma unroll
    for (int r = 0; r < 4; r++) {
      const float* rowp = ip + ry[r] * IW;
      float rs = wx[0] * rowp[rx[0]] + wx[1] * rowp[rx[1]] +
                 wx[2] * rowp[rx[2]] + wx[3] * rowp[rx[3]];
      acc += wy[r] * rs;
    }
    rimg[((size_t)(b * 3 + c)) * HW + p] = acc;
  } else {
    // ---- sigs part: float4, 4 px/thread, LDS float4 reduce ----
    const int sid = gid - (GRAM_BLOCKS + RIMG_BLOCKS);
    const int b = sid / (HW / 256);
    const int pblk = sid % (HW / 256);
    const int lane = threadIdx.x & 63;
    const int cg = threadIdx.x >> 6;         // 0..3
    const int p0 = pblk * 256 + lane * 4;

    const float* ib = inp + (size_t)b * CF * HW + (size_t)cg * 16 * HW + p0;
    float4 acc = {0.f, 0.f, 0.f, 0.f};
#pragma unroll
    for (int c = 0; c < 16; c++) {
      const float4 v = *reinterpret_cast<const float4*>(ib + (size_t)c * HW);
      const float wc = w_comp[cg * 16 + c];
      acc.x += v.x * wc; acc.y += v.y * wc;
      acc.z += v.z * wc; acc.w += v.w * wc;
    }
    red4[threadIdx.x] = acc;
    __syncthreads();
    if (threadIdx.x < 64) {
      const float4 a = red4[threadIdx.x];
      const float4 b1 = red4[threadIdx.x + 64];
      const float4 c1 = red4[threadIdx.x + 128];
      const float4 d = red4[threadIdx.x + 192];
      float4 s;
      s.x = (a.x + b1.x) + (c1.x + d.x);
      s.y = (a.y + b1.y) + (c1.y + d.y);
      s.z = (a.z + b1.z) + (c1.z + d.z);
      s.w = (a.w + b1.w) + (c1.w + d.w);
      s.x = 1.f / (1.f + expf(-s.x));
      s.y = 1.f / (1.f + expf(-s.y));
      s.z = 1.f / (1.f + expf(-s.z));
      s.w = 1.f / (1.f + expf(-s.w));
      *reinterpret_cast<float4*>(sigs + (size_t)b * HW +
                                 pblk * 256 + threadIdx.x * 4) = s;
    }
  }
}

// ---------------------------------------------------------------------------
// phigather (unchanged from the 121.7us R4 config: 4 px/thread, 8 ch/block,
// 1024 blocks = 4 waves/SIMD; the 512-block variant was the R2 regression).
// Window trick: all x-dependent neighbor reads use an 8-wide window
// [x0-2 .. x0+5]: L=float2@max(x0-2,0), C=float4@x0, R=float2@min(x0+4,W-2);
// value(kx, px j) = a[j+2*kx]. Out-of-range taps have phi==0 (zero-pad),
// so clamped window entries may hold garbage safely.
// ---------------------------------------------------------------------------
__global__ __launch_bounds__(256) void phigather_kernel(
    const float* __restrict__ inp, const float* __restrict__ rimg,
    const float* __restrict__ sigs, const float* __restrict__ Mt,
    const float* __restrict__ GXX, const float* __restrict__ GYY,
    const float* __restrict__ G, float* __restrict__ out)
{
  const int cg = blockIdx.x;                             // 0..7, 8 channels
  const int p0 = (blockIdx.y * 256 + threadIdx.x) * 4;   // 4 px per thread
  const int b = blockIdx.z;
  const int x0 = p0 & (W - 1);
  const int y  = p0 >> 8;

  const int xl = max(x0 - 2, 0);          // 8B-aligned
  const int xr = min(x0 + 4, W - 2);      // 8B-aligned

  int rowoff[3];
  bool vrow[3];
#pragma unroll
  for (int ky = 0; ky < 3; ky++) {
    const int cy = y + 2 * (ky - 1);
    vrow[ky] = ((unsigned)cy < (unsigned)H);
    rowoff[ky] = min(max(cy, 0), H - 1) * W;
  }

  const float* rb = rimg + (size_t)b * 3 * HW;
  const float* sb = sigs + (size_t)b * HW;

  // t = G^T r per pixel (float4 lanes = the 4 pixels)
  const float4 r0 = *reinterpret_cast<const float4*>(rb + p0);
  const float4 r1 = *reinterpret_cast<const float4*>(rb + HW + p0);
  const float4 r2 = *reinterpret_cast<const float4*>(rb + 2 * HW + p0);
  float4 t0, t1, t2;
  {
    const float g0 = G[0], g1 = G[1], g2 = G[2];
    const float g3 = G[3], g4 = G[4], g5 = G[5];
    const float g6 = G[6], g7 = G[7], g8 = G[8];
    t0.x = r0.x * g0 + r1.x * g3 + r2.x * g6;
    t0.y = r0.y * g0 + r1.y * g3 + r2.y * g6;
    t0.z = r0.z * g0 + r1.z * g3 + r2.z * g6;
    t0.w = r0.w * g0 + r1.w * g3 + r2.w * g6;
    t1.x = r0.x * g1 + r1.x * g4 + r2.x * g7;
    t1.y = r0.y * g1 + r1.y * g4 + r2.y * g7;
    t1.z = r0.z * g1 + r1.z * g4 + r2.z * g7;
    t1.w = r0.w * g1 + r1.w * g4 + r2.w * g7;
    t2.x = r0.x * g2 + r1.x * g5 + r2.x * g8;
    t2.y = r0.y * g2 + r1.y * g5 + r2.y * g8;
    t2.z = r0.z * g2 + r1.z * g5 + r2.z * g8;
    t2.w = r0.w * g2 + r1.w * g5 + r2.w * g8;
  }

  // Mt row-y window (shared by all ky)
  float mrow[8];
  {
    const float2 L = *reinterpret_cast<const float2*>(Mt + y * W + xl);
    const float4 C = *reinterpret_cast<const float4*>(Mt + y * W + x0);
    const float2 R = *reinterpret_cast<const float2*>(Mt + y * W + xr);
    mrow[0] = L.x; mrow[1] = L.y; mrow[2] = C.x; mrow[3] = C.y;
    mrow[4] = C.z; mrow[5] = C.w; mrow[6] = R.x; mrow[7] = R.y;
  }
  // GXX[kx][x0..x0+3] (aligned)
  float4 gxxv[3];
#pragma unroll
  for (int kx = 0; kx < 3; kx++)
    gxxv[kx] = *reinterpret_cast<const float4*>(GXX + kx * 256 + x0);

  float4 ph[9];
#pragma unroll
  for (int ky = 0; ky < 3; ky++) {
    const int ro = rowoff[ky];
    float a0[8], a1[8], a2[8], as_[8];
    {
      const float2 L0 = *reinterpret_cast<const float2*>(rb + ro + xl);
      const float4 C0 = *reinterpret_cast<const float4*>(rb + ro + x0);
      const float2 R0 = *reinterpret_cast<const float2*>(rb + ro + xr);
      a0[0]=L0.x; a0[1]=L0.y; a0[2]=C0.x; a0[3]=C0.y;
      a0[4]=C0.z; a0[5]=C0.w; a0[6]=R0.x; a0[7]=R0.y;
      const float2 L1 = *reinterpret_cast<const float2*>(rb + HW + ro + xl);
      const float4 C1 = *reinterpret_cast<const float4*>(rb + HW + ro + x0);
      const float2 R1 = *reinterpret_cast<const float2*>(rb + HW + ro + xr);
      a1[0]=L1.x; a1[1]=L1.y; a1[2]=C1.x; a1[3]=C1.y;
      a1[4]=C1.z; a1[5]=C1.w; a1[6]=R1.x; a1[7]=R1.y;
      const float2 L2 = *reinterpret_cast<const float2*>(rb + 2 * HW + ro + xl);
      const float4 C2 = *reinterpret_cast<const float4*>(rb + 2 * HW + ro + x0);
      const float2 R2 = *reinterpret_cast<const float2*>(rb + 2 * HW + ro + xr);
      a2[0]=L2.x; a2[1]=L2.y; a2[2]=C2.x; a2[3]=C2.y;
      a2[4]=C2.z; a2[5]=C2.w; a2[6]=R2.x; a2[7]=R2.y;
      const float2 Ls = *reinterpret_cast<const float2*>(sb + ro + xl);
      const float4 Cs = *reinterpret_cast<const float4*>(sb + ro + x0);
      const float2 Rs = *reinterpret_cast<const float2*>(sb + ro + xr);
      as_[0]=Ls.x; as_[1]=Ls.y; as_[2]=Cs.x; as_[3]=Cs.y;
      as_[4]=Cs.z; as_[5]=Cs.w; as_[6]=Rs.x; as_[7]=Rs.y;
    }
    const float4 mc = *reinterpret_cast<const float4*>(Mt + ro + x0);
    const float gyy = GYY[ky * 256 + y];

#pragma unroll
    for (int kx = 0; kx < 3; kx++) {
      float4 p;
      {
        const int rel = 0 + 2 * kx;
        const float fs = t0.x * a0[rel] + t1.x * a1[rel] + t2.x * a2[rel]
                       + gxxv[kx].x + gyy + mrow[rel] + mc.x;
        const bool v = vrow[ky] && ((unsigned)(x0 + 0 + 2 * (kx - 1)) < (unsigned)W);
        p.x = v ? as_[rel] * fs : 0.f;
      }
      {
        const int rel = 1 + 2 * kx;
        const float fs = t0.y * a0[rel] + t1.y * a1[rel] + t2.y * a2[rel]
                       + gxxv[kx].y + gyy + mrow[rel] + mc.y;
        const bool v = vrow[ky] && ((unsigned)(x0 + 1 + 2 * (kx - 1)) < (unsigned)W);
        p.y = v ? as_[rel] * fs : 0.f;
      }
      {
        const int rel = 2 + 2 * kx;
        const float fs = t0.z * a0[rel] + t1.z * a1[rel] + t2.z * a2[rel]
                       + gxxv[kx].z + gyy + mrow[rel] + mc.z;
        const bool v = vrow[ky] && ((unsigned)(x0 + 2 + 2 * (kx - 1)) < (unsigned)W);
        p.z = v ? as_[rel] * fs : 0.f;
      }
      {
        const int rel = 3 + 2 * kx;
        const float fs = t0.w * a0[rel] + t1.w * a1[rel] + t2.w * a2[rel]
                       + gxxv[kx].w + gyy + mrow[rel] + mc.w;
        const bool v = vrow[ky] && ((unsigned)(x0 + 3 + 2 * (kx - 1)) < (unsigned)W);
        p.w = v ? as_[rel] * fs : 0.f;
      }
      ph[ky * 3 + kx] = p;
    }
  }

  // phase 2: 8 channels, float4 in/out
  const float* ib = inp + ((size_t)b * CF + cg * 8) * HW;
  float* ob = out + ((size_t)b * CF + cg * 8) * HW + p0;
#pragma unroll 4
  for (int c = 0; c < 8; c++) {
    const float* ic = ib + (size_t)c * HW;
    float4 acc = {0.f, 0.f, 0.f, 0.f};
#pragma unroll
    for (int ky = 0; ky < 3; ky++) {
      const int ro = rowoff[ky];
      const float2 L = *reinterpret_cast<const float2*>(ic + ro + xl);
      const float4 C = *reinterpret_cast<const float4*>(ic + ro + x0);
      const float2 R = *reinterpret_cast<const float2*>(ic + ro + xr);
      const float a[8] = {L.x, L.y, C.x, C.y, C.z, C.w, R.x, R.y};
#pragma unroll
      for (int kx = 0; kx < 3; kx++) {
        const float4 w = ph[ky * 3 + kx];
        acc.x += w.x * a[0 + 2 * kx];
        acc.y += w.y * a[1 + 2 * kx];
        acc.z += w.z * a[2 + 2 * kx];
        acc.w += w.w * a[3 + 2 * kx];
      }
    }
    *reinterpret_cast<float4*>(ob + (size_t)c * HW) = acc;
  }
}

// ---------------------------------------------------------------------------
extern "C" void kernel_launch(void* const* d_in, const int* in_sizes, int n_in,
                              void* d_out, int out_size, void* d_ws, size_t ws_size,
                              hipStream_t stream)
{
  const float* inp    = (const float*)d_in[0];
  const float* img    = (const float*)d_in[1];
  const float* w_pos  = (const float*)d_in[2];
  const float* w_img  = (const float*)d_in[3];
  const float* w_comp = (const float*)d_in[4];
  float* out = (float*)d_out;
  float* ws  = (float*)d_ws;

  float* Mt   = ws + OFF_MT;
  float* GXX  = ws + OFF_GXX;
  float* GYY  = ws + OFF_GYY;
  float* G    = ws + OFF_G;
  float* rimg = ws + OFF_RIMG;
  float* sigs = ws + OFF_S;
  float* PX   = ws + OFF_PX;
  float* PY   = ws + OFF_PY;

  hipLaunchKernelGGL(pxy_kernel, dim3(32), dim3(256), 0, stream, w_pos, PX, PY);

  hipLaunchKernelGGL(prep_kernel, dim3(PREP_BLOCKS), dim3(256), 0, stream,
                     img, inp, w_comp, w_img, PX, PY,
                     rimg, sigs, Mt, GXX, GYY, G);

  hipLaunchKernelGGL(phigather_kernel, dim3(8, HW / 1024, Bn), dim3(256), 0, stream,
                     inp, rimg, sigs, Mt, GXX, GYY, G, out);
}